// Round 1
// baseline (234.618 us; speedup 1.0000x reference)
//
#include <hip/hip_runtime.h>
#include <cmath>

#define BINS 10
#define EDGE_TOP (1.0f + 1e-6f)

// Classify one element: bin index (clipped to [0,9]) and g value.
// Near-bin-boundary values are recomputed with double-precision exp so the
// fp32-rounded result matches a correctly-rounded fp32 exp (numpy parity).
__device__ __forceinline__ void ghm_classify(float p, int& bin, float& g_out) {
    float ef  = expf(-p);
    float g   = fabsf(ef - 1.0f);
    float g10 = g * 10.0f;
    int   b   = (int)g10;          // g >= 0, trunc == floor
    float fb  = (float)b;
    bool hazard = (g10 - fb < 1e-4f) || (fb + 1.0f - g10 < 1e-4f) ||
                  (fabsf(g - EDGE_TOP) < 4e-6f);
    if (hazard) {
        double ed = exp(-(double)p);
        float ef2 = (float)ed;     // ~correctly-rounded fp32 exp
        g   = fabsf(ef2 - 1.0f);
        g10 = g * 10.0f;
        b   = (int)g10;
    }
    bin   = (b < 9) ? b : 9;
    g_out = g;
}

// Pass 1: histogram of in-bin valid samples per bin + total valid count.
__global__ __launch_bounds__(256) void ghm_hist(
    const float* __restrict__ pred, const float* __restrict__ lw,
    unsigned int* __restrict__ cnt, int n)
{
    unsigned int c[BINS + 1];
#pragma unroll
    for (int b = 0; b <= BINS; ++b) c[b] = 0;

    const int tid    = blockIdx.x * blockDim.x + threadIdx.x;
    const int stride = gridDim.x * blockDim.x;
    const int n4     = n >> 2;
    const float4* p4 = (const float4*)pred;
    const float4* w4 = (const float4*)lw;

    for (int i = tid; i < n4; i += stride) {
        float4 p = p4[i];
        float4 w = w4[i];
        float ps[4] = {p.x, p.y, p.z, p.w};
        float ws[4] = {w.x, w.y, w.z, w.w};
#pragma unroll
        for (int k = 0; k < 4; ++k) {
            bool valid = ws[k] > 0.0f;
            c[BINS] += valid ? 1u : 0u;
            int bin; float g;
            ghm_classify(ps[k], bin, g);
            bool ib = valid && (g < EDGE_TOP);
#pragma unroll
            for (int b = 0; b < BINS; ++b)
                c[b] += (ib && (bin == b)) ? 1u : 0u;
        }
    }
    // scalar tail (n % 4 elements), handled by one thread
    if (tid == 0) {
        for (int i = n4 << 2; i < n; ++i) {
            bool valid = lw[i] > 0.0f;
            c[BINS] += valid ? 1u : 0u;
            int bin; float g;
            ghm_classify(pred[i], bin, g);
            bool ib = valid && (g < EDGE_TOP);
#pragma unroll
            for (int b = 0; b < BINS; ++b)
                c[b] += (ib && (bin == b)) ? 1u : 0u;
        }
    }

    // wave reduce (64 lanes) -> LDS -> one global atomic per block per slot
    __shared__ unsigned int sc[BINS + 1];
    if (threadIdx.x < BINS + 1) sc[threadIdx.x] = 0;
    __syncthreads();
#pragma unroll
    for (int b = 0; b <= BINS; ++b) {
        unsigned int v = c[b];
#pragma unroll
        for (int off = 32; off > 0; off >>= 1)
            v += __shfl_down(v, off, 64);
        if ((threadIdx.x & 63) == 0) atomicAdd(&sc[b], v);
    }
    __syncthreads();
    if (threadIdx.x < BINS + 1) atomicAdd(&cnt[threadIdx.x], sc[threadIdx.x]);
}

// Pass 2: per-bin final weight, replicating the reference's fp32 op order:
// w = (tot / counts[b]) / n   for nonempty bins, else 0.
__global__ void ghm_finalize(const unsigned int* __restrict__ cnt,
                             float* __restrict__ wfinal)
{
    if (threadIdx.x == 0 && blockIdx.x == 0) {
        float tot = fmaxf((float)cnt[BINS], 1.0f);
        int n = 0;
        for (int b = 0; b < BINS; ++b) n += (cnt[b] > 0) ? 1 : 0;
        float nf = fmaxf((float)n, 1.0f);
        for (int b = 0; b < BINS; ++b) {
            float w = 0.0f;
            if (cnt[b] > 0) {
                w = tot / (float)cnt[b];   // tot / max(counts,1), counts>0
                if (n > 0) w = w / nf;     // weights / max(n,1)
            }
            wfinal[b] = w;
        }
    }
}

// Pass 3: out = in_bin ? w[bin] * pred : 0
__global__ __launch_bounds__(256) void ghm_apply(
    const float* __restrict__ pred, const float* __restrict__ lw,
    const float* __restrict__ wfinal, float* __restrict__ out, int n)
{
    __shared__ float wf[BINS];
    if (threadIdx.x < BINS) wf[threadIdx.x] = wfinal[threadIdx.x];
    __syncthreads();

    const int tid    = blockIdx.x * blockDim.x + threadIdx.x;
    const int stride = gridDim.x * blockDim.x;
    const int n4     = n >> 2;
    const float4* p4 = (const float4*)pred;
    const float4* w4 = (const float4*)lw;
    float4* o4       = (float4*)out;

    for (int i = tid; i < n4; i += stride) {
        float4 p = p4[i];
        float4 w = w4[i];
        float ps[4] = {p.x, p.y, p.z, p.w};
        float ws[4] = {w.x, w.y, w.z, w.w};
        float os[4];
#pragma unroll
        for (int k = 0; k < 4; ++k) {
            bool valid = ws[k] > 0.0f;
            int bin; float g;
            ghm_classify(ps[k], bin, g);
            bool ib = valid && (g < EDGE_TOP);
            os[k] = ib ? wf[bin] * ps[k] : 0.0f;
        }
        float4 o;
        o.x = os[0]; o.y = os[1]; o.z = os[2]; o.w = os[3];
        o4[i] = o;
    }
    if (tid == 0) {
        for (int i = n4 << 2; i < n; ++i) {
            bool valid = lw[i] > 0.0f;
            int bin; float g;
            ghm_classify(pred[i], bin, g);
            bool ib = valid && (g < EDGE_TOP);
            out[i] = ib ? wfinal[bin] * pred[i] : 0.0f;
        }
    }
}

extern "C" void kernel_launch(void* const* d_in, const int* in_sizes, int n_in,
                              void* d_out, int out_size, void* d_ws, size_t ws_size,
                              hipStream_t stream)
{
    const float* pred = (const float*)d_in[0];
    // d_in[1] = target, unused by the math
    const float* lw   = (const float*)d_in[2];
    float* out        = (float*)d_out;
    const int n       = in_sizes[0];

    unsigned int* cnt = (unsigned int*)d_ws;     // [0..9]=bin counts, [10]=valid
    float* wfinal     = ((float*)d_ws) + 16;     // 64B offset, 10 floats

    // ws is poisoned 0xAA before every call — zero the counters on-stream.
    hipMemsetAsync(d_ws, 0, (BINS + 1) * sizeof(unsigned int), stream);

    dim3 block(256);
    dim3 grid(2048);
    ghm_hist<<<grid, block, 0, stream>>>(pred, lw, cnt, n);
    ghm_finalize<<<1, 64, 0, stream>>>(cnt, wfinal);
    ghm_apply<<<grid, block, 0, stream>>>(pred, lw, wfinal, out, n);
}